// Round 1
// baseline (11105.093 us; speedup 1.0000x reference)
//
#include <hip/hip_runtime.h>
#include <hip/hip_bf16.h>
#include <math.h>

#define HDIM 768
#define SDIM 512
#define VDIM 30522
#define BDIM 8
#define TLEN 32
#define H3 2304
#define VT 31034          // V + S
#define CB 61556          // 2V + S
#define NEGV -1.0e6f
#define OFF2 ((size_t)BDIM * TLEN * VT)   // 7944704

// ---------------------------------------------------------------------------
// Generic batched mat-vec: y[b*ystride + i] = dot(W[i,:], xv[b,:]) + bias[i]
// One wave per output row i, computing all B=8 batches (x vectors in LDS).
// block = 512 threads (8 waves). Dynamic LDS = B*K floats.
// ---------------------------------------------------------------------------
__global__ void matvec8_kernel(const float* __restrict__ W,
                               const float* __restrict__ xv,
                               const float* __restrict__ bias,
                               float* __restrict__ y,
                               int N, int K, int ystride, int negfirst)
{
    extern __shared__ float xs[];
    int nf4 = BDIM * K / 4;
    for (int i = threadIdx.x; i < nf4; i += blockDim.x)
        ((float4*)xs)[i] = ((const float4*)xv)[i];
    __syncthreads();

    int wid  = threadIdx.x >> 6;
    int lane = threadIdx.x & 63;
    int row  = blockIdx.x * (blockDim.x >> 6) + wid;
    if (row >= N) return;

    const float* wrow = W + (size_t)row * K;
    float acc[BDIM];
#pragma unroll
    for (int b = 0; b < BDIM; b++) acc[b] = 0.f;

    for (int k4 = lane; k4 < K / 4; k4 += 64) {
        float4 w4 = ((const float4*)wrow)[k4];
#pragma unroll
        for (int b = 0; b < BDIM; b++) {
            float4 x4 = ((const float4*)(xs + b * K))[k4];
            acc[b] += w4.x * x4.x + w4.y * x4.y + w4.z * x4.z + w4.w * x4.w;
        }
    }
#pragma unroll
    for (int b = 0; b < BDIM; b++) {
        float v = acc[b];
        for (int off = 32; off; off >>= 1) v += __shfl_down(v, off, 64);
        if (lane == 0) {
            float r = v + (bias ? bias[row] : 0.f);
            if (negfirst && row == 0) r = NEGV;
            y[(size_t)b * ystride + row] = r;
        }
    }
}

// ---------------------------------------------------------------------------
// Attention: scores = enc[b] @ th[b]; softmax; context -> x[b, 0:H)
// One block (512 threads) per batch element.
// ---------------------------------------------------------------------------
__global__ void attn_kernel(const float* __restrict__ enc,
                            const float* __restrict__ th,
                            float* __restrict__ x)
{
    __shared__ float sth[HDIM];
    __shared__ float sw[SDIM];
    __shared__ float red[8];
    int b = blockIdx.x, tid = threadIdx.x;
    for (int i = tid; i < HDIM; i += 512) sth[i] = th[b * HDIM + i];
    __syncthreads();

    // scores: one thread per s
    {
        int s = tid;
        const float4* er = (const float4*)(enc + ((size_t)b * SDIM + s) * HDIM);
        const float4* tr = (const float4*)sth;
        float a = 0.f;
        for (int k4 = 0; k4 < HDIM / 4; k4++) {
            float4 e = er[k4], t = tr[k4];
            a += e.x * t.x + e.y * t.y + e.z * t.z + e.w * t.w;
        }
        sw[s] = a;
    }
    __syncthreads();

    // softmax over sw[512]
    int wid = tid >> 6, lane = tid & 63;
    float m = sw[tid];
    for (int off = 32; off; off >>= 1) m = fmaxf(m, __shfl_down(m, off, 64));
    if (lane == 0) red[wid] = m;
    __syncthreads();
    if (tid == 0) {
        float mm = red[0];
        for (int w = 1; w < 8; w++) mm = fmaxf(mm, red[w]);
        red[0] = mm;
    }
    __syncthreads();
    float M = red[0];
    __syncthreads();
    float e = expf(sw[tid] - M);
    float zs = e;
    for (int off = 32; off; off >>= 1) zs += __shfl_down(zs, off, 64);
    if (lane == 0) red[wid] = zs;
    __syncthreads();
    if (tid == 0) {
        float z = 0.f;
        for (int w = 0; w < 8; w++) z += red[w];
        red[0] = z;
    }
    __syncthreads();
    float Z = red[0];
    sw[tid] = e / Z;
    __syncthreads();

    // context: coalesced column reads
    for (int h = tid; h < HDIM; h += 512) {
        float c = 0.f;
        for (int s = 0; s < SDIM; s++)
            c += sw[s] * enc[((size_t)b * SDIM + s) * HDIM + h];
        x[b * H3 + h] = c;
    }
}

// ---------------------------------------------------------------------------
// GRU gate combine: h_new = (1-z)*n + z*h
// ---------------------------------------------------------------------------
__global__ void gru_combine_kernel(const float* __restrict__ gi,
                                   const float* __restrict__ gh,
                                   float* __restrict__ h)
{
    int i = blockIdx.x * 256 + threadIdx.x;
    if (i >= BDIM * HDIM) return;
    int b = i / HDIM, j = i % HDIM;
    float gir = gi[b * H3 + j],        ghr = gh[b * H3 + j];
    float giz = gi[b * H3 + HDIM + j], ghz = gh[b * H3 + HDIM + j];
    float gin = gi[b * H3 + 2*HDIM + j], ghn = gh[b * H3 + 2*HDIM + j];
    float r = 1.f / (1.f + expf(-(gir + ghr)));
    float z = 1.f / (1.f + expf(-(giz + ghz)));
    float n = tanhf(gin + r * ghn);
    float ho = h[i];
    h[i] = (1.f - z) * n + z * ho;
}

// ---------------------------------------------------------------------------
// Copy-score sequence: css[b,s] = dot(enc[b,s,:], th2[b,:])
// ---------------------------------------------------------------------------
__global__ void css_kernel(const float* __restrict__ enc,
                           const float* __restrict__ th2,
                           float* __restrict__ css)
{
    __shared__ float sth[HDIM];
    int b = blockIdx.x, tid = threadIdx.x;
    for (int i = tid; i < HDIM; i += 512) sth[i] = th2[b * HDIM + i];
    __syncthreads();
    int s = tid;
    const float4* er = (const float4*)(enc + ((size_t)b * SDIM + s) * HDIM);
    const float4* tr = (const float4*)sth;
    float a = 0.f;
    for (int k4 = 0; k4 < HDIM / 4; k4++) {
        float4 e = er[k4], t = tr[k4];
        a += e.x * t.x + e.y * t.y + e.z * t.z + e.w * t.w;
    }
    css[b * SDIM + s] = a;
}

// ---------------------------------------------------------------------------
// Deterministic copy-scatter: comb[b, V+tok] = sum of css at positions of tok.
// First-occurrence thread does the (ascending) sum. tok==0 stays NEG (forced
// missing). Non-present tokens keep their one-time NEG init.
// ---------------------------------------------------------------------------
__global__ void copy_kernel(const int* __restrict__ inputs,
                            const float* __restrict__ css,
                            float* __restrict__ comb)
{
    __shared__ int toks[SDIM];
    __shared__ float vals[SDIM];
    int b = blockIdx.x, s = threadIdx.x;
    toks[s] = inputs[b * SDIM + s];
    vals[s] = css[b * SDIM + s];
    __syncthreads();
    int tok = toks[s];
    if (tok != 0) {
        bool first = true;
        for (int s2 = 0; s2 < s; s2++)
            if (toks[s2] == tok) { first = false; break; }
        if (first) {
            float sum = 0.f;
            for (int s2 = s; s2 < SDIM; s2++)
                if (toks[s2] == tok) sum += vals[s2];
            comb[(size_t)b * CB + VDIM + tok] = sum;
        }
    }
}

// ---------------------------------------------------------------------------
// Softmax over comb[b, 0:2V) (tail [2V,2V+S) is const NEG -> exp==0 exactly),
// final_probs = p_gen + p_copy, log, write output row, argmax -> samp.
// One block (1024 threads) per batch element.
// ---------------------------------------------------------------------------
__global__ void softmax_out_kernel(const float* __restrict__ comb,
                                   float* __restrict__ dout,
                                   int* __restrict__ samp, int t)
{
    __shared__ float sred[1024];
    __shared__ int sidx[1024];
    int b = blockIdx.x, tid = threadIdx.x;
    const float* row = comb + (size_t)b * CB;
    const int n = 2 * VDIM;

    float m = -INFINITY;
    for (int i = tid; i < n; i += 1024) m = fmaxf(m, row[i]);
    sred[tid] = m; __syncthreads();
    for (int off = 512; off; off >>= 1) {
        if (tid < off) sred[tid] = fmaxf(sred[tid], sred[tid + off]);
        __syncthreads();
    }
    float M = sred[0]; __syncthreads();

    float zs = 0.f;
    for (int i = tid; i < n; i += 1024) zs += expf(row[i] - M);
    sred[tid] = zs; __syncthreads();
    for (int off = 512; off; off >>= 1) {
        if (tid < off) sred[tid] += sred[tid + off];
        __syncthreads();
    }
    float Z = sred[0]; __syncthreads();

    float* orow = dout + ((size_t)b * TLEN + t + 1) * VT;
    float best = -INFINITY; int bidx = 0;
    for (int v = tid; v < VDIM; v += 1024) {
        float pg = expf(row[v] - M) / Z;
        float pc = expf(row[VDIM + v] - M) / Z;
        float lp = logf(pg + pc + 1e-10f);
        orow[v] = lp;
        if (lp > best) { best = lp; bidx = v; }
    }
    const float LPT = logf(1e-10f);
    for (int j = tid; j < SDIM; j += 1024) orow[VDIM + j] = LPT;

    sred[tid] = best; sidx[tid] = bidx; __syncthreads();
    for (int off = 512; off; off >>= 1) {
        if (tid < off) {
            float v2 = sred[tid + off]; int i2 = sidx[tid + off];
            if (v2 > sred[tid] || (v2 == sred[tid] && i2 < sidx[tid])) {
                sred[tid] = v2; sidx[tid] = i2;
            }
        }
        __syncthreads();
    }
    if (tid == 0) {
        samp[b] = sidx[0];
        dout[OFF2 + b * TLEN + t + 1] = (float)sidx[0];
    }
}

// ---------------------------------------------------------------------------
// Selective read + embedding for next step: x[b, H:2H) = sel, x[b, 2H:3H)=emb.
// One block (768 threads) per batch element.
// ---------------------------------------------------------------------------
__global__ void sel_embed_kernel(const float* __restrict__ enc,
                                 const float* __restrict__ css,
                                 const int* __restrict__ inputs,
                                 const int* __restrict__ samp,
                                 const float* __restrict__ emb,
                                 float* __restrict__ x)
{
    __shared__ int midx[SDIM];
    __shared__ float mco[SDIM];
    __shared__ unsigned char flag[SDIM];
    __shared__ int mcount;
    __shared__ float sden;
    int b = blockIdx.x, tid = threadIdx.x;
    int sv = samp[b];
    if (tid < SDIM) flag[tid] = (inputs[b * SDIM + tid] == sv) ? 1 : 0;
    __syncthreads();
    if (tid == 0) {
        int c = 0; float den = 0.f;
        for (int s = 0; s < SDIM; s++)
            if (flag[s]) {
                midx[c] = s;
                float v = css[b * SDIM + s];
                mco[c] = v;
                den += fabsf(v);
                c++;
            }
        mcount = c;
        sden = fmaxf(den, 1e-12f);
    }
    __syncthreads();
    int c = mcount; float den = sden;
    float sel = 0.f;
    for (int mI = 0; mI < c; mI++)
        sel += (mco[mI] / den) * enc[((size_t)b * SDIM + midx[mI]) * HDIM + tid];
    x[b * H3 + HDIM + tid] = sel;

    int ic = (sv > VDIM) ? 3 : (sv >= VDIM ? VDIM - 1 : sv);
    x[b * H3 + 2 * HDIM + tid] = emb[(size_t)ic * HDIM + tid];
}

// ---------------------------------------------------------------------------
// Init kernels
// ---------------------------------------------------------------------------
__global__ void init_state_kernel(float* __restrict__ h,
                                  float* __restrict__ x,
                                  const float* __restrict__ emb)
{
    int i = blockIdx.x * 256 + threadIdx.x;
    if (i >= BDIM * HDIM) return;
    int b = i / HDIM, j = i % HDIM;
    h[i] = 0.f;
    x[b * H3 + HDIM + j] = 0.f;                 // sel = 0
    x[b * H3 + 2 * HDIM + j] = emb[HDIM + j];   // embedded(idx=1)
}

__global__ void init_comb_kernel(float* __restrict__ comb)
{
    int i = blockIdx.x * 256 + threadIdx.x;
    if (i >= BDIM * VT) return;
    int b = i / VT, j = i % VT;
    comb[(size_t)b * CB + VDIM + j] = NEGV;
}

__global__ void init_out_kernel(float* __restrict__ dout,
                                const int* __restrict__ cls)
{
    int i = blockIdx.x * 256 + threadIdx.x;
    if (i >= BDIM * VT) return;
    int b = i / VT, v = i % VT;
    dout[(size_t)b * TLEN * VT + v] = (v == 0) ? (float)cls[0] : 0.f;
    if (v == 0) dout[OFF2 + b * TLEN] = 1.0f;
}

// ---------------------------------------------------------------------------
extern "C" void kernel_launch(void* const* d_in, const int* in_sizes, int n_in,
                              void* d_out, int out_size, void* d_ws, size_t ws_size,
                              hipStream_t stream)
{
    const float* enc    = (const float*)d_in[0];
    const int*   inputs = (const int*)d_in[1];
    const int*   cls    = (const int*)d_in[2];
    const float* emb    = (const float*)d_in[4];
    const float* attn_w = (const float*)d_in[5];
    const float* attn_b = (const float*)d_in[6];
    const float* copy_w = (const float*)d_in[7];
    const float* copy_b = (const float*)d_in[8];
    const float* w_ih   = (const float*)d_in[9];
    const float* w_hh   = (const float*)d_in[10];
    const float* b_ih   = (const float*)d_in[11];
    const float* b_hh   = (const float*)d_in[12];
    const float* out_w  = (const float*)d_in[13];
    const float* out_b  = (const float*)d_in[14];
    float* dout = (float*)d_out;

    float* ws  = (float*)d_ws;
    float* h   = ws;                       // B*H
    float* x   = h   + BDIM * HDIM;        // B*3H
    float* th  = x   + BDIM * H3;          // B*H
    float* th2 = th  + BDIM * HDIM;        // B*H
    float* gi  = th2 + BDIM * HDIM;        // B*3H
    float* gh  = gi  + BDIM * H3;          // B*3H
    float* css = gh  + BDIM * H3;          // B*S
    float* comb = css + BDIM * SDIM;       // B*CB
    int*   samp = (int*)(comb + (size_t)BDIM * CB);

    init_state_kernel<<<(BDIM * HDIM + 255) / 256, 256, 0, stream>>>(h, x, emb);
    init_comb_kernel<<<(BDIM * VT + 255) / 256, 256, 0, stream>>>(comb);
    init_out_kernel<<<(BDIM * VT + 255) / 256, 256, 0, stream>>>(dout, cls);

    for (int t = 0; t < TLEN - 1; t++) {
        // th = h @ attn_w.T + attn_b
        matvec8_kernel<<<96, 512, BDIM * HDIM * 4, stream>>>(
            attn_w, h, attn_b, th, HDIM, HDIM, HDIM, 0);
        // attention -> context into x[:, 0:H)
        attn_kernel<<<BDIM, 512, 0, stream>>>(enc, th, x);
        // GRU gates
        matvec8_kernel<<<288, 512, BDIM * H3 * 4, stream>>>(
            w_ih, x, b_ih, gi, H3, H3, H3, 0);
        matvec8_kernel<<<288, 512, BDIM * HDIM * 4, stream>>>(
            w_hh, h, b_hh, gh, H3, HDIM, H3, 0);
        gru_combine_kernel<<<24, 256, 0, stream>>>(gi, gh, h);
        // copy scores
        matvec8_kernel<<<96, 512, BDIM * HDIM * 4, stream>>>(
            copy_w, h, copy_b, th2, HDIM, HDIM, HDIM, 0);
        css_kernel<<<BDIM, 512, 0, stream>>>(enc, th2, css);
        // generation scores -> comb[:, 0:V)
        matvec8_kernel<<<(VDIM + 7) / 8, 512, BDIM * HDIM * 4, stream>>>(
            out_w, h, out_b, comb, VDIM, HDIM, CB, 1);
        // copy scatter -> comb[:, V:2V)
        copy_kernel<<<BDIM, SDIM, 0, stream>>>(inputs, css, comb);
        // softmax + output + argmax
        softmax_out_kernel<<<BDIM, 1024, 0, stream>>>(comb, dout, samp, t);
        // selective read + embedding for next step
        sel_embed_kernel<<<BDIM, HDIM, 0, stream>>>(enc, css, inputs, samp, emb, x);
    }
}

// Round 3
// 7074.886 us; speedup vs baseline: 1.5696x; 1.5696x over previous
//
#include <hip/hip_runtime.h>
#include <hip/hip_bf16.h>
#include <math.h>

#define HDIM 768
#define SDIM 512
#define VDIM 30522
#define BDIM 8
#define TLEN 32
#define H3   2304
#define VT   31034          // V + S
#define NEGV -1.0e6f
#define OFF2 ((size_t)BDIM * TLEN * VT)   // 7944704

// ---------------------------------------------------------------------------
// Dual batched mat-vec over two stacked weight matrices sharing input xv:
//   rows [0, n1)     : y1[b*ys1 + r]      = dot(W1[r,:], xv[b,:]) + B1[r]
//   rows [n1, N)     : y2[b*ys2 + (r-n1)] = dot(W2[r-n1,:], xv[b,:]) + B2[..]
// One wave per row, all 8 batches per wave. block=512 (8 waves).
// stage=1: copy xv (B*K floats) to dynamic LDS first (use for K*B*4 <= 48KB).
// ---------------------------------------------------------------------------
__global__ __launch_bounds__(512) void matvec_dual_kernel(
    const float* __restrict__ W1, const float* __restrict__ B1,
    float* __restrict__ Y1, int ys1, int n1,
    const float* __restrict__ W2, const float* __restrict__ B2,
    float* __restrict__ Y2, int ys2, int negfirst2,
    const float* __restrict__ xv, int K, int N, int stage)
{
    extern __shared__ float xs[];
    if (stage) {
        int nf4 = BDIM * K / 4;
        for (int i = threadIdx.x; i < nf4; i += blockDim.x)
            ((float4*)xs)[i] = ((const float4*)xv)[i];
        __syncthreads();
    }
    const float* xbase = stage ? xs : xv;

    int wid  = threadIdx.x >> 6;
    int lane = threadIdx.x & 63;
    int row  = blockIdx.x * 8 + wid;
    if (row >= N) return;

    const float* wrow; const float* bias; float* y; int ys; int r; bool neg = false;
    if (row < n1) {
        r = row; wrow = W1 + (size_t)r * K; bias = B1; y = Y1; ys = ys1;
    } else {
        r = row - n1; wrow = W2 + (size_t)r * K; bias = B2; y = Y2; ys = ys2;
        neg = (negfirst2 && r == 0);
    }

    float acc[BDIM];
#pragma unroll
    for (int b = 0; b < BDIM; b++) acc[b] = 0.f;

    for (int k4 = lane; k4 < K / 4; k4 += 64) {
        float4 w4 = ((const float4*)wrow)[k4];
#pragma unroll
        for (int b = 0; b < BDIM; b++) {
            float4 x4 = ((const float4*)(xbase + b * K))[k4];
            acc[b] += w4.x * x4.x + w4.y * x4.y + w4.z * x4.z + w4.w * x4.w;
        }
    }
#pragma unroll
    for (int b = 0; b < BDIM; b++) {
        float v = acc[b];
        for (int off = 32; off; off >>= 1) v += __shfl_down(v, off, 64);
        if (lane == 0) {
            float rr = neg ? NEGV : (v + bias[r]);
            y[(size_t)b * ys + r] = rr;
        }
    }
}

// ---------------------------------------------------------------------------
// Attention: scores = enc[b] @ th[b]; softmax over 512; context -> x[b, 0:H)
// One block (512 threads) per batch element.
// ---------------------------------------------------------------------------
__global__ __launch_bounds__(512) void attn_kernel(
    const float* __restrict__ enc, const float* __restrict__ th,
    float* __restrict__ x)
{
    __shared__ float sth[HDIM];
    __shared__ float sw[SDIM];
    __shared__ float red[8];
    __shared__ float4 ctxp[2][HDIM / 4];
    int b = blockIdx.x, tid = threadIdx.x;
    for (int i = tid; i < HDIM; i += 512) sth[i] = th[b * HDIM + i];
    __syncthreads();

    // scores: one thread per s
    {
        int s = tid;
        const float4* er = (const float4*)(enc + ((size_t)b * SDIM + s) * HDIM);
        const float4* tr = (const float4*)sth;
        float a = 0.f;
        for (int k4 = 0; k4 < HDIM / 4; k4++) {
            float4 e = er[k4], t = tr[k4];
            a += e.x * t.x + e.y * t.y + e.z * t.z + e.w * t.w;
        }
        sw[s] = a;
    }
    __syncthreads();

    // softmax over sw[512]
    int wid = tid >> 6, lane = tid & 63;
    float m = sw[tid];
    for (int off = 32; off; off >>= 1) m = fmaxf(m, __shfl_down(m, off, 64));
    if (lane == 0) red[wid] = m;
    __syncthreads();
    if (tid == 0) {
        float mm = red[0];
        for (int w = 1; w < 8; w++) mm = fmaxf(mm, red[w]);
        red[0] = mm;
    }
    __syncthreads();
    float M = red[0];
    __syncthreads();
    float e = expf(sw[tid] - M);
    float zs = e;
    for (int off = 32; off; off >>= 1) zs += __shfl_down(zs, off, 64);
    if (lane == 0) red[wid] = zs;
    __syncthreads();
    if (tid == 0) {
        float z = 0.f;
        for (int w = 0; w < 8; w++) z += red[w];
        red[0] = z;
    }
    __syncthreads();
    float Z = red[0];
    sw[tid] = e / Z;
    __syncthreads();

    // context: float4 columns, s-range split in two halves
    int c = tid % (HDIM / 4);
    int sg = tid / (HDIM / 4);
    if (sg < 2) {
        float4 acc = make_float4(0.f, 0.f, 0.f, 0.f);
        const float4* eb = (const float4*)(enc + (size_t)b * SDIM * HDIM);
        for (int s = sg * 256; s < sg * 256 + 256; s++) {
            float w = sw[s];
            float4 e = eb[s * (HDIM / 4) + c];
            acc.x += w * e.x; acc.y += w * e.y; acc.z += w * e.z; acc.w += w * e.w;
        }
        ctxp[sg][c] = acc;
    }
    __syncthreads();
    if (tid < HDIM / 4) {
        float4 p0 = ctxp[0][tid], p1 = ctxp[1][tid];
        float4 r4 = make_float4(p0.x + p1.x, p0.y + p1.y, p0.z + p1.z, p0.w + p1.w);
        ((float4*)(x + b * H3))[tid] = r4;
    }
}

// ---------------------------------------------------------------------------
// GRU gate combine: h = (1-z)*n + z*h   (in place)
// ---------------------------------------------------------------------------
__global__ __launch_bounds__(256) void gru_combine_kernel(
    const float* __restrict__ gi, const float* __restrict__ gh,
    float* __restrict__ h)
{
    int i = blockIdx.x * 256 + threadIdx.x;
    if (i >= BDIM * HDIM) return;
    int b = i / HDIM, j = i % HDIM;
    float gir = gi[b * H3 + j],          ghr = gh[b * H3 + j];
    float giz = gi[b * H3 + HDIM + j],   ghz = gh[b * H3 + HDIM + j];
    float gin = gi[b * H3 + 2*HDIM + j], ghn = gh[b * H3 + 2*HDIM + j];
    float r = 1.f / (1.f + expf(-(gir + ghr)));
    float z = 1.f / (1.f + expf(-(giz + ghz)));
    float n = tanhf(gin + r * ghn);
    float ho = h[i];
    h[i] = (1.f - z) * n + z * ho;
}

// ---------------------------------------------------------------------------
// Fused tail: css -> copy aggregation -> softmax(gen + copy) -> log_probs row
// -> argmax -> selective read + embedding for next step.
// One block (1024 threads) per batch element.
// ---------------------------------------------------------------------------
__global__ __launch_bounds__(1024) void tail_kernel(
    const float* __restrict__ enc, const float* __restrict__ th2,
    const float* __restrict__ gen, const int* __restrict__ inputs,
    const float* __restrict__ emb, float* __restrict__ dout,
    float* __restrict__ x, int t)
{
    __shared__ float th2s[HDIM];
    __shared__ int   toks[SDIM];
    __shared__ float csss[SDIM];
    __shared__ float aggv[SDIM];
    __shared__ unsigned char ffl[SDIM];
    __shared__ float redf[1024];
    __shared__ int   redi[1024];
    __shared__ int   mlist[SDIM];
    __shared__ float mscore[SDIM];
    __shared__ int   wcnt[16];
    __shared__ int   woff[16];
    __shared__ int   mtot;

    int b = blockIdx.x, tid = threadIdx.x;

    for (int i = tid; i < HDIM; i += 1024) th2s[i] = th2[b * HDIM + i];
    if (tid < SDIM) toks[tid] = inputs[b * SDIM + tid];
    __syncthreads();

    // --- css[s] = dot(enc[b,s,:], th2[b,:]) : 2 threads per s -------------
    {
        int s = tid >> 1, half = tid & 1;
        const float4* er = (const float4*)(enc + ((size_t)b * SDIM + s) * HDIM + half * (HDIM / 2));
        const float4* tr = (const float4*)(th2s + half * (HDIM / 2));
        float a = 0.f;
        for (int k = 0; k < HDIM / 8; k++) {
            float4 e = er[k], t4 = tr[k];
            a += e.x * t4.x + e.y * t4.y + e.z * t4.z + e.w * t4.w;
        }
        a += __shfl_xor(a, 1, 64);
        if (half == 0) csss[s] = a;
    }
    __syncthreads();

    // --- copy aggregation: first occurrence sums all duplicates -----------
    if (tid < SDIM) {
        int tok = toks[tid]; int isf = 0; float agg = -INFINITY;
        if (tok != 0) {
            isf = 1;
            for (int s2 = 0; s2 < tid; s2++)
                if (toks[s2] == tok) { isf = 0; break; }
            if (isf) {
                float ss = 0.f;
                for (int s2 = tid; s2 < SDIM; s2++)
                    if (toks[s2] == tok) ss += csss[s2];
                agg = ss;
            }
        }
        ffl[tid] = (unsigned char)isf;
        aggv[tid] = agg;
    }
    __syncthreads();

    // --- softmax max pass -------------------------------------------------
    const float* grow = gen + (size_t)b * VDIM;
    float m = -INFINITY;
    for (int v = tid; v < VDIM; v += 1024) m = fmaxf(m, grow[v]);
    if (tid < SDIM && ffl[tid]) m = fmaxf(m, aggv[tid]);
    redf[tid] = m; __syncthreads();
    for (int off = 512; off; off >>= 1) {
        if (tid < off) redf[tid] = fmaxf(redf[tid], redf[tid + off]);
        __syncthreads();
    }
    float M = redf[0]; __syncthreads();

    // --- softmax sum pass -------------------------------------------------
    float z = 0.f;
    for (int v = tid; v < VDIM; v += 1024) z += expf(grow[v] - M);
    if (tid < SDIM && ffl[tid]) z += expf(aggv[tid] - M);
    redf[tid] = z; __syncthreads();
    for (int off = 512; off; off >>= 1) {
        if (tid < off) redf[tid] += redf[tid + off];
        __syncthreads();
    }
    float Z = redf[0]; __syncthreads();
    float invZ = 1.f / Z;

    // --- output pass + thread-local argmax --------------------------------
    float* orow = dout + ((size_t)b * TLEN + t + 1) * VT;
    float best = -INFINITY; int bidx = 2147483647;
    for (int v = tid; v < VDIM; v += 1024) {
        float pg = expf(grow[v] - M) * invZ;
        float lp = logf(pg + 1e-10f);
        orow[v] = lp;
        if (lp > best) { best = lp; bidx = v; }
    }
    if (tid < SDIM) orow[VDIM + tid] = logf(1e-10f);
    __syncthreads();   // before present-token overwrites (write-write)

    if (tid < SDIM && ffl[tid]) {
        int tok = toks[tid];
        float pc = expf(aggv[tid] - M) * invZ;
        float pg = expf(grow[tok] - M) * invZ;
        float lp = logf(pg + pc + 1e-10f);
        orow[tok] = lp;
        if (lp > best || (lp == best && tok < bidx)) { best = lp; bidx = tok; }
    }
    redf[tid] = best; redi[tid] = bidx; __syncthreads();
    for (int off = 512; off; off >>= 1) {
        if (tid < off) {
            float v2 = redf[tid + off]; int i2 = redi[tid + off];
            if (v2 > redf[tid] || (v2 == redf[tid] && i2 < redi[tid])) {
                redf[tid] = v2; redi[tid] = i2;
            }
        }
        __syncthreads();
    }
    int samp = redi[0];
    if (tid == 0) dout[OFF2 + (size_t)b * TLEN + t + 1] = (float)samp;
    __syncthreads();

    // --- selective read ---------------------------------------------------
    int flag = (tid < SDIM) ? (toks[tid] == samp) : 0;
    float dv = flag ? fabsf(csss[tid]) : 0.f;
    redf[tid] = dv; __syncthreads();
    for (int off = 512; off; off >>= 1) {
        if (tid < off) redf[tid] += redf[tid + off];
        __syncthreads();
    }
    float den = fmaxf(redf[0], 1e-12f);
    __syncthreads();

    // deterministic s-ascending match compaction via ballot
    unsigned long long mk = __ballot(flag);
    int wv = tid >> 6, ln = tid & 63;
    if (ln == 0) wcnt[wv] = __popcll(mk);
    __syncthreads();
    if (tid == 0) {
        int o = 0;
        for (int w = 0; w < 16; w++) { woff[w] = o; o += wcnt[w]; }
        mtot = o;
    }
    __syncthreads();
    if (flag) {
        int pos = woff[wv] + __popcll(mk & ((1ULL << ln) - 1ULL));
        mlist[pos] = tid;
        mscore[pos] = csss[tid] / den;
    }
    __syncthreads();
    int mc = mtot;

    if (tid < HDIM) {
        float sel = 0.f;
        for (int mI = 0; mI < mc; mI++) {
            int s = mlist[mI];
            sel += mscore[mI] * enc[((size_t)b * SDIM + s) * HDIM + tid];
        }
        x[b * H3 + HDIM + tid] = sel;
        int ic = (samp > VDIM) ? 3 : samp;
        if (ic >= VDIM) ic = VDIM - 1;
        x[b * H3 + 2 * HDIM + tid] = emb[(size_t)ic * HDIM + tid];
    }
}

// ---------------------------------------------------------------------------
// Init kernels
// ---------------------------------------------------------------------------
__global__ __launch_bounds__(256) void init_state_kernel(
    float* __restrict__ h, float* __restrict__ x, const float* __restrict__ emb)
{
    int i = blockIdx.x * 256 + threadIdx.x;
    if (i >= BDIM * HDIM) return;
    int b = i / HDIM, j = i % HDIM;
    h[i] = 0.f;
    x[b * H3 + HDIM + j] = 0.f;                 // sel = 0
    x[b * H3 + 2 * HDIM + j] = emb[HDIM + j];   // embedded(idx=1)
}

__global__ __launch_bounds__(256) void init_out_kernel(
    float* __restrict__ dout, const int* __restrict__ cls)
{
    int i = blockIdx.x * 256 + threadIdx.x;
    if (i >= BDIM * VT) return;
    int b = i / VT, v = i % VT;
    dout[(size_t)b * TLEN * VT + v] = (v == 0) ? (float)cls[0] : 0.f;
    if (v == 0) dout[OFF2 + (size_t)b * TLEN] = 1.0f;
}

// ---------------------------------------------------------------------------
extern "C" void kernel_launch(void* const* d_in, const int* in_sizes, int n_in,
                              void* d_out, int out_size, void* d_ws, size_t ws_size,
                              hipStream_t stream)
{
    const float* enc    = (const float*)d_in[0];
    const int*   inputs = (const int*)d_in[1];
    const int*   cls    = (const int*)d_in[2];
    const float* emb    = (const float*)d_in[4];
    const float* attn_w = (const float*)d_in[5];
    const float* attn_b = (const float*)d_in[6];
    const float* copy_w = (const float*)d_in[7];
    const float* copy_b = (const float*)d_in[8];
    const float* w_ih   = (const float*)d_in[9];
    const float* w_hh   = (const float*)d_in[10];
    const float* b_ih   = (const float*)d_in[11];
    const float* b_hh   = (const float*)d_in[12];
    const float* out_w  = (const float*)d_in[13];
    const float* out_b  = (const float*)d_in[14];
    float* dout = (float*)d_out;

    float* ws   = (float*)d_ws;
    float* h    = ws;                        // B*H      = 6144
    float* x    = h   + BDIM * HDIM;         // B*3H     = 18432
    float* th   = x   + BDIM * H3;           // B*H
    float* th2  = th  + BDIM * HDIM;         // B*H
    float* gi   = th2 + BDIM * HDIM;         // B*3H
    float* gh   = gi  + BDIM * H3;           // B*3H
    float* gen  = gh  + BDIM * H3;           // B*V      = 244176

    init_state_kernel<<<(BDIM * HDIM + 255) / 256, 256, 0, stream>>>(h, x, emb);
    init_out_kernel<<<(BDIM * VT + 255) / 256, 256, 0, stream>>>(dout, cls);

    const int LDS768 = BDIM * HDIM * 4;   // 24 KB

    for (int t = 0; t < TLEN - 1; t++) {
        // th = h@attn_w.T + attn_b ; gh = h@w_hh.T + b_hh   (fused, N=3072)
        matvec_dual_kernel<<<(HDIM + H3) / 8, 512, LDS768, stream>>>(
            attn_w, attn_b, th, HDIM, HDIM,
            w_hh, b_hh, gh, H3, 0,
            h, HDIM, HDIM + H3, 1);
        // attention -> context into x[:, 0:H)
        attn_kernel<<<BDIM, 512, 0, stream>>>(enc, th, x);
        // gi = x@w_ih.T + b_ih  (K=2304: no LDS staging)
        matvec_dual_kernel<<<H3 / 8, 512, 0, stream>>>(
            w_ih, b_ih, gi, H3, H3,
            w_ih, b_ih, gi, H3, 0,
            x, H3, H3, 0);
        // h' = combine(gi, gh, h)
        gru_combine_kernel<<<(BDIM * HDIM + 255) / 256, 256, 0, stream>>>(gi, gh, h);
        // th2 = h'@copy_w.T ; gen = h'@out_w.T (row0 -> NEG)   (fused, N=31290)
        matvec_dual_kernel<<<(HDIM + VDIM + 7) / 8, 512, LDS768, stream>>>(
            copy_w, copy_b, th2, HDIM, HDIM,
            out_w, out_b, gen, VDIM, 1,
            h, HDIM, HDIM + VDIM, 1);
        // css/copy/softmax/argmax/output/sel/embed
        tail_kernel<<<BDIM, 1024, 0, stream>>>(enc, th2, gen, inputs, emb, dout, x, t);
    }
}

// Round 4
// 4538.517 us; speedup vs baseline: 2.4469x; 1.5589x over previous
//
#include <hip/hip_runtime.h>
#include <hip/hip_bf16.h>
#include <math.h>

#define HDIM 768
#define SDIM 512
#define VDIM 30522
#define BDIM 8
#define TLEN 32
#define H3   2304
#define VT   31034          // V + S
#define NEGV -1.0e6f
#define OFF2 ((size_t)BDIM * TLEN * VT)   // 7944704
#define SUBS 8
#define SSLICE (SDIM / SUBS)      // 64
#define VSLICE 3816               // ceil(VDIM/8); last slice = 3810

// ---------------------------------------------------------------------------
// Dual batched mat-vec over two stacked weight matrices sharing input xv.
// One wave per row, all 8 batches per wave. block = 512 (8 waves).
// ---------------------------------------------------------------------------
__global__ __launch_bounds__(512) void matvec_dual_kernel(
    const float* __restrict__ W1, const float* __restrict__ B1,
    float* __restrict__ Y1, int ys1, int n1,
    const float* __restrict__ W2, const float* __restrict__ B2,
    float* __restrict__ Y2, int ys2, int negfirst2,
    const float* __restrict__ xv, int K, int N, int stage)
{
    extern __shared__ float xs[];
    if (stage) {
        int nf4 = BDIM * K / 4;
        for (int i = threadIdx.x; i < nf4; i += blockDim.x)
            ((float4*)xs)[i] = ((const float4*)xv)[i];
        __syncthreads();
    }
    const float* xbase = stage ? xs : xv;

    int wid  = threadIdx.x >> 6;
    int lane = threadIdx.x & 63;
    int row  = blockIdx.x * 8 + wid;
    if (row >= N) return;

    const float* wrow; const float* bias; float* y; int ys; int r; bool neg = false;
    if (row < n1) {
        r = row; wrow = W1 + (size_t)r * K; bias = B1; y = Y1; ys = ys1;
    } else {
        r = row - n1; wrow = W2 + (size_t)r * K; bias = B2; y = Y2; ys = ys2;
        neg = (negfirst2 && r == 0);
    }

    float acc[BDIM];
#pragma unroll
    for (int b = 0; b < BDIM; b++) acc[b] = 0.f;

    for (int k4 = lane; k4 < K / 4; k4 += 64) {
        float4 w4 = ((const float4*)wrow)[k4];
#pragma unroll
        for (int b = 0; b < BDIM; b++) {
            float4 x4 = ((const float4*)(xbase + b * K))[k4];
            acc[b] += w4.x * x4.x + w4.y * x4.y + w4.z * x4.z + w4.w * x4.w;
        }
    }
#pragma unroll
    for (int b = 0; b < BDIM; b++) {
        float v = acc[b];
        for (int off = 32; off; off >>= 1) v += __shfl_down(v, off, 64);
        if (lane == 0) {
            float rr = neg ? NEGV : (v + bias[r]);
            y[(size_t)b * ys + r] = rr;
        }
    }
}

// ---------------------------------------------------------------------------
// Attention part: block (b,sub). Scores for s in [sub*64,(sub+1)*64), then
// unnormalized partial context c_sub = sum exp(score - m_sub) * enc row,
// plus (m_sub, z_sub). 512 threads (8 waves).
// ---------------------------------------------------------------------------
__global__ __launch_bounds__(512) void attn_part_kernel(
    const float* __restrict__ enc, const float* __restrict__ th,
    float* __restrict__ attnC, float* __restrict__ attnM,
    float* __restrict__ attnZ)
{
    __shared__ float sth[HDIM];
    __shared__ float sw[SSLICE];
    __shared__ float smz[2];
    int blk = blockIdx.x, b = blk >> 3, sub = blk & 7;
    int tid = threadIdx.x, wid = tid >> 6, lane = tid & 63;
    int slo = sub * SSLICE;

    for (int i = tid; i < HDIM; i += 512) sth[i] = th[b * HDIM + i];
    __syncthreads();

    // scores: wave `wid` handles s = slo + wid*8 + j
    for (int j = 0; j < 8; j++) {
        int s = slo + wid * 8 + j;
        const float4* er = (const float4*)(enc + ((size_t)b * SDIM + s) * HDIM);
        const float4* tr = (const float4*)sth;
        float a = 0.f;
#pragma unroll
        for (int i = 0; i < 3; i++) {
            float4 e = er[lane + i * 64], t4 = tr[lane + i * 64];
            a += e.x * t4.x + e.y * t4.y + e.z * t4.z + e.w * t4.w;
        }
        for (int off = 32; off; off >>= 1) a += __shfl_down(a, off, 64);
        if (lane == 0) sw[wid * 8 + j] = a;
    }
    __syncthreads();

    // local softmax pieces over the 64 scores (single wave, tid<64)
    if (tid < 64) {
        float v = sw[tid];
        float m = v;
        for (int off = 32; off; off >>= 1) m = fmaxf(m, __shfl_xor(m, off, 64));
        float e = expf(v - m);
        float z = e;
        for (int off = 32; off; off >>= 1) z += __shfl_xor(z, off, 64);
        sw[tid] = e;
        if (tid == 0) { smz[0] = m; smz[1] = z; }
    }
    __syncthreads();
    if (tid == 0) {
        attnM[b * 8 + sub] = smz[0];
        attnZ[b * 8 + sub] = smz[1];
    }

    // partial context: col-parallel, coalesced
    for (int col = tid; col < HDIM; col += 512) {
        float acc = 0.f;
        const float* eb = enc + ((size_t)b * SDIM + slo) * HDIM + col;
        for (int s2 = 0; s2 < SSLICE; s2++)
            acc += sw[s2] * eb[s2 * HDIM];
        attnC[((size_t)b * 8 + sub) * HDIM + col] = acc;
    }
}

// ---------------------------------------------------------------------------
// Attention finalize: x[b,0:H) = sum_sub C_sub * exp(m_sub - M) / Z
// 8 blocks x 768 threads.
// ---------------------------------------------------------------------------
__global__ __launch_bounds__(768) void attn_fin_kernel(
    const float* __restrict__ attnC, const float* __restrict__ attnM,
    const float* __restrict__ attnZ, float* __restrict__ x)
{
    int b = blockIdx.x, col = threadIdx.x;
    float m[8], z[8];
#pragma unroll
    for (int i = 0; i < 8; i++) { m[i] = attnM[b * 8 + i]; z[i] = attnZ[b * 8 + i]; }
    float M = m[0];
#pragma unroll
    for (int i = 1; i < 8; i++) M = fmaxf(M, m[i]);
    float Z = 0.f;
#pragma unroll
    for (int i = 0; i < 8; i++) Z += z[i] * expf(m[i] - M);
    float invZ = 1.f / Z;
    float acc = 0.f;
#pragma unroll
    for (int i = 0; i < 8; i++)
        acc += attnC[((size_t)b * 8 + i) * HDIM + col] * expf(m[i] - M);
    x[b * H3 + col] = acc * invZ;
}

// ---------------------------------------------------------------------------
// GRU gate combine: h = (1-z)*n + z*h   (in place)
// ---------------------------------------------------------------------------
__global__ __launch_bounds__(256) void gru_combine_kernel(
    const float* __restrict__ gi, const float* __restrict__ gh,
    float* __restrict__ h)
{
    int i = blockIdx.x * 256 + threadIdx.x;
    if (i >= BDIM * HDIM) return;
    int b = i / HDIM, j = i % HDIM;
    float gir = gi[b * H3 + j],          ghr = gh[b * H3 + j];
    float giz = gi[b * H3 + HDIM + j],   ghz = gh[b * H3 + HDIM + j];
    float gin = gi[b * H3 + 2*HDIM + j], ghn = gh[b * H3 + 2*HDIM + j];
    float r = 1.f / (1.f + expf(-(gir + ghr)));
    float z = 1.f / (1.f + expf(-(giz + ghz)));
    float n = tanhf(gin + r * ghn);
    float ho = h[i];
    h[i] = (1.f - z) * n + z * ho;
}

// ---------------------------------------------------------------------------
// Tail AB: block (b,sub). (1) css for s-slice; (2) gen (max,sumexp) partial
// for v-slice. 512 threads.
// ---------------------------------------------------------------------------
__global__ __launch_bounds__(512) void tail_ab_kernel(
    const float* __restrict__ enc, const float* __restrict__ th2,
    const float* __restrict__ gen, float* __restrict__ css,
    float* __restrict__ genM, float* __restrict__ genZ)
{
    __shared__ float sth[HDIM];
    __shared__ float red[8];
    int blk = blockIdx.x, b = blk >> 3, sub = blk & 7;
    int tid = threadIdx.x, wid = tid >> 6, lane = tid & 63;
    int slo = sub * SSLICE;

    for (int i = tid; i < HDIM; i += 512) sth[i] = th2[b * HDIM + i];
    __syncthreads();

    // css slice
    for (int j = 0; j < 8; j++) {
        int s = slo + wid * 8 + j;
        const float4* er = (const float4*)(enc + ((size_t)b * SDIM + s) * HDIM);
        const float4* tr = (const float4*)sth;
        float a = 0.f;
#pragma unroll
        for (int i = 0; i < 3; i++) {
            float4 e = er[lane + i * 64], t4 = tr[lane + i * 64];
            a += e.x * t4.x + e.y * t4.y + e.z * t4.z + e.w * t4.w;
        }
        for (int off = 32; off; off >>= 1) a += __shfl_down(a, off, 64);
        if (lane == 0) css[b * SDIM + s] = a;
    }

    // gen partial (m, z) over v-slice
    int vlo = sub * VSLICE;
    int vhi = min(VDIM, vlo + VSLICE);
    const float* grow = gen + (size_t)b * VDIM;
    float m = -INFINITY;
    for (int v = vlo + tid; v < vhi; v += 512) m = fmaxf(m, grow[v]);
    for (int off = 32; off; off >>= 1) m = fmaxf(m, __shfl_xor(m, off, 64));
    if (lane == 0) red[wid] = m;
    __syncthreads();
    float M = red[0];
#pragma unroll
    for (int w = 1; w < 8; w++) M = fmaxf(M, red[w]);
    float z = 0.f;
    for (int v = vlo + tid; v < vhi; v += 512) z += expf(grow[v] - M);
    for (int off = 32; off; off >>= 1) z += __shfl_xor(z, off, 64);
    __syncthreads();
    if (lane == 0) red[wid] = z;
    __syncthreads();
    if (tid == 0) {
        float Z = 0.f;
#pragma unroll
        for (int w = 0; w < 8; w++) Z += red[w];
        genM[b * 8 + sub] = M;
        genZ[b * 8 + sub] = Z;
    }
}

// ---------------------------------------------------------------------------
// Tail C: block (b,sub). Redundant (identical) copy aggregation + M/Z
// combine; write log-prob slice (+ copy overwrites in-slice); per-slice
// argmax partial. 1024 threads.
// ---------------------------------------------------------------------------
__global__ __launch_bounds__(1024) void tail_c_kernel(
    const float* __restrict__ gen, const float* __restrict__ css,
    const int* __restrict__ inputs, const float* __restrict__ genM,
    const float* __restrict__ genZ, float* __restrict__ dout,
    float* __restrict__ argV, int* __restrict__ argI, int t)
{
    __shared__ int   toks[SDIM];
    __shared__ float csss[SDIM];
    __shared__ float aggv[SDIM];
    __shared__ unsigned char ffl[SDIM];
    __shared__ float redf[1024];
    __shared__ int   redi[1024];
    int blk = blockIdx.x, b = blk >> 3, sub = blk & 7;
    int tid = threadIdx.x;

    if (tid < SDIM) {
        toks[tid] = inputs[b * SDIM + tid];
        csss[tid] = css[b * SDIM + tid];
    }
    __syncthreads();

    // copy aggregation (identical in all 8 sub-blocks of a batch)
    if (tid < SDIM) {
        int tok = toks[tid]; int isf = 0; float agg = -INFINITY;
        if (tok != 0) {
            isf = 1;
            for (int s2 = 0; s2 < tid; s2++)
                if (toks[s2] == tok) { isf = 0; break; }
            if (isf) {
                float ss = 0.f;
                for (int s2 = tid; s2 < SDIM; s2++)
                    if (toks[s2] == tok) ss += csss[s2];
                agg = ss;
            }
        }
        ffl[tid] = (unsigned char)isf;
        aggv[tid] = agg;
    }
    __syncthreads();

    // copy (m9, z9): fixed-order LDS tree over 512 slots
    redf[tid] = (tid < SDIM && ffl[tid]) ? aggv[tid] : -INFINITY;
    __syncthreads();
    for (int off = 512; off; off >>= 1) {
        if (tid < off) redf[tid] = fmaxf(redf[tid], redf[tid + off]);
        __syncthreads();
    }
    float m9 = redf[0]; __syncthreads();
    redf[tid] = (tid < SDIM && ffl[tid] && m9 > -INFINITY)
                    ? expf(aggv[tid] - m9) : 0.f;
    __syncthreads();
    for (int off = 512; off; off >>= 1) {
        if (tid < off) redf[tid] += redf[tid + off];
        __syncthreads();
    }
    float z9 = redf[0]; __syncthreads();

    // global M, Z (deterministic fixed order; identical across sub-blocks)
    float M = genM[b * 8 + 0];
#pragma unroll
    for (int i = 1; i < 8; i++) M = fmaxf(M, genM[b * 8 + i]);
    if (m9 > -INFINITY) M = fmaxf(M, m9);
    float Z = 0.f;
#pragma unroll
    for (int i = 0; i < 8; i++) Z += genZ[b * 8 + i] * expf(genM[b * 8 + i] - M);
    if (m9 > -INFINITY) Z += z9 * expf(m9 - M);
    float invZ = 1.f / Z;

    // log-prob slice + thread-local argmax
    const float* grow = gen + (size_t)b * VDIM;
    float* orow = dout + ((size_t)b * TLEN + t + 1) * VT;
    int vlo = sub * VSLICE;
    int vhi = min(VDIM, vlo + VSLICE);
    float best = -INFINITY; int bidx = 2147483647;
    for (int v = vlo + tid; v < vhi; v += 1024) {
        float pg = expf(grow[v] - M) * invZ;
        float lp = logf(pg + 1e-10f);
        orow[v] = lp;
        if (lp > best) { best = lp; bidx = v; }
    }
    if (sub == 0 && tid < SDIM) orow[VDIM + tid] = logf(1e-10f);
    __syncthreads();

    // copy overwrites for first-occurrence tokens in this slice
    if (tid < SDIM && ffl[tid]) {
        int tok = toks[tid];
        if (tok >= vlo && tok < vhi) {
            float pc = expf(aggv[tid] - M) * invZ;
            float pg = expf(grow[tok] - M) * invZ;
            float lp = logf(pg + pc + 1e-10f);
            orow[tok] = lp;
            if (lp > best || (lp == best && tok < bidx)) { best = lp; bidx = tok; }
        }
    }
    redf[tid] = best; redi[tid] = bidx; __syncthreads();
    for (int off = 512; off; off >>= 1) {
        if (tid < off) {
            float v2 = redf[tid + off]; int i2 = redi[tid + off];
            if (v2 > redf[tid] || (v2 == redf[tid] && i2 < redi[tid])) {
                redf[tid] = v2; redi[tid] = i2;
            }
        }
        __syncthreads();
    }
    if (tid == 0) { argV[b * 8 + sub] = redf[0]; argI[b * 8 + sub] = redi[0]; }
}

// ---------------------------------------------------------------------------
// Tail D: combine argmax partials -> samp; selective read + embed.
// 8 blocks x 1024 threads.
// ---------------------------------------------------------------------------
__global__ __launch_bounds__(1024) void tail_d_kernel(
    const float* __restrict__ enc, const float* __restrict__ css,
    const int* __restrict__ inputs, const float* __restrict__ argV,
    const int* __restrict__ argI, const float* __restrict__ emb,
    float* __restrict__ dout, float* __restrict__ x, int t)
{
    __shared__ int   toks[SDIM];
    __shared__ float csss[SDIM];
    __shared__ float redf[1024];
    __shared__ int   mlist[SDIM];
    __shared__ float mscore[SDIM];
    __shared__ int   wcnt[16];
    __shared__ int   woff[16];
    __shared__ int   mtot;
    int b = blockIdx.x, tid = threadIdx.x;

    // argmax combine: ascending sub, strictly-greater wins -> lowest index
    float best = argV[b * 8 + 0]; int samp = argI[b * 8 + 0];
#pragma unroll
    for (int i = 1; i < 8; i++) {
        float v = argV[b * 8 + i];
        if (v > best) { best = v; samp = argI[b * 8 + i]; }
    }
    if (tid == 0) dout[OFF2 + (size_t)b * TLEN + t + 1] = (float)samp;

    if (tid < SDIM) {
        toks[tid] = inputs[b * SDIM + tid];
        csss[tid] = css[b * SDIM + tid];
    }
    __syncthreads();

    int flag = (tid < SDIM) ? (toks[tid] == samp) : 0;
    float dv = flag ? fabsf(csss[tid]) : 0.f;
    redf[tid] = dv; __syncthreads();
    for (int off = 512; off; off >>= 1) {
        if (tid < off) redf[tid] += redf[tid + off];
        __syncthreads();
    }
    float den = fmaxf(redf[0], 1e-12f);
    __syncthreads();

    unsigned long long mk = __ballot(flag);
    int wv = tid >> 6, ln = tid & 63;
    if (ln == 0) wcnt[wv] = __popcll(mk);
    __syncthreads();
    if (tid == 0) {
        int o = 0;
        for (int w = 0; w < 16; w++) { woff[w] = o; o += wcnt[w]; }
        mtot = o;
    }
    __syncthreads();
    if (flag) {
        int pos = woff[wv] + __popcll(mk & ((1ULL << ln) - 1ULL));
        mlist[pos] = tid;
        mscore[pos] = csss[tid] / den;
    }
    __syncthreads();
    int mc = mtot;

    if (tid < HDIM) {
        float sel = 0.f;
        for (int mI = 0; mI < mc; mI++) {
            int s = mlist[mI];
            sel += mscore[mI] * enc[((size_t)b * SDIM + s) * HDIM + tid];
        }
        x[b * H3 + HDIM + tid] = sel;
        int ic = (samp > VDIM) ? 3 : samp;
        if (ic >= VDIM) ic = VDIM - 1;
        x[b * H3 + 2 * HDIM + tid] = emb[(size_t)ic * HDIM + tid];
    }
}

// ---------------------------------------------------------------------------
// Init kernels
// ---------------------------------------------------------------------------
__global__ __launch_bounds__(256) void init_state_kernel(
    float* __restrict__ h, float* __restrict__ x, const float* __restrict__ emb)
{
    int i = blockIdx.x * 256 + threadIdx.x;
    if (i >= BDIM * HDIM) return;
    int b = i / HDIM, j = i % HDIM;
    h[i] = 0.f;
    x[b * H3 + HDIM + j] = 0.f;                 // sel = 0
    x[b * H3 + 2 * HDIM + j] = emb[HDIM + j];   // embedded(idx=1)
}

__global__ __launch_bounds__(256) void init_out_kernel(
    float* __restrict__ dout, const int* __restrict__ cls)
{
    int i = blockIdx.x * 256 + threadIdx.x;
    if (i >= BDIM * VT) return;
    int b = i / VT, v = i % VT;
    dout[(size_t)b * TLEN * VT + v] = (v == 0) ? (float)cls[0] : 0.f;
    if (v == 0) dout[OFF2 + (size_t)b * TLEN] = 1.0f;
}

// ---------------------------------------------------------------------------
extern "C" void kernel_launch(void* const* d_in, const int* in_sizes, int n_in,
                              void* d_out, int out_size, void* d_ws, size_t ws_size,
                              hipStream_t stream)
{
    const float* enc    = (const float*)d_in[0];
    const int*   inputs = (const int*)d_in[1];
    const int*   cls    = (const int*)d_in[2];
    const float* emb    = (const float*)d_in[4];
    const float* attn_w = (const float*)d_in[5];
    const float* attn_b = (const float*)d_in[6];
    const float* copy_w = (const float*)d_in[7];
    const float* copy_b = (const float*)d_in[8];
    const float* w_ih   = (const float*)d_in[9];
    const float* w_hh   = (const float*)d_in[10];
    const float* b_ih   = (const float*)d_in[11];
    const float* b_hh   = (const float*)d_in[12];
    const float* out_w  = (const float*)d_in[13];
    const float* out_b  = (const float*)d_in[14];
    float* dout = (float*)d_out;

    float* ws    = (float*)d_ws;
    float* h     = ws;                         // B*H
    float* x     = h     + BDIM * HDIM;        // B*3H
    float* th    = x     + BDIM * H3;          // B*H
    float* th2   = th    + BDIM * HDIM;        // B*H
    float* gi    = th2   + BDIM * HDIM;        // B*3H
    float* gh    = gi    + BDIM * H3;          // B*3H
    float* gen   = gh    + BDIM * H3;          // B*V
    float* css   = gen   + (size_t)BDIM * VDIM;// B*S
    float* attnC = css   + BDIM * SDIM;        // B*8*H
    float* attnM = attnC + BDIM * 8 * HDIM;    // 64
    float* attnZ = attnM + 64;                 // 64
    float* genM  = attnZ + 64;                 // 64
    float* genZ  = genM  + 64;                 // 64
    float* argV  = genZ  + 64;                 // 64
    int*   argI  = (int*)(argV + 64);          // 64

    init_state_kernel<<<(BDIM * HDIM + 255) / 256, 256, 0, stream>>>(h, x, emb);
    init_out_kernel<<<(BDIM * VT + 255) / 256, 256, 0, stream>>>(dout, cls);

    const int LDS768 = BDIM * HDIM * 4;   // 24 KB

    for (int t = 0; t < TLEN - 1; t++) {
        // th = h@attn_w.T + attn_b ; gh = h@w_hh.T + b_hh
        matvec_dual_kernel<<<(HDIM + H3) / 8, 512, LDS768, stream>>>(
            attn_w, attn_b, th, HDIM, HDIM,
            w_hh, b_hh, gh, H3, 0,
            h, HDIM, HDIM + H3, 1);
        // attention partials + combine -> x[:, 0:H)
        attn_part_kernel<<<64, 512, 0, stream>>>(enc, th, attnC, attnM, attnZ);
        attn_fin_kernel<<<BDIM, 768, 0, stream>>>(attnC, attnM, attnZ, x);
        // gi = x@w_ih.T + b_ih
        matvec_dual_kernel<<<H3 / 8, 512, 0, stream>>>(
            w_ih, b_ih, gi, H3, H3,
            w_ih, b_ih, gi, H3, 0,
            x, H3, H3, 0);
        // h' = combine(gi, gh, h)
        gru_combine_kernel<<<(BDIM * HDIM + 255) / 256, 256, 0, stream>>>(gi, gh, h);
        // th2 = h'@copy_w.T ; gen = h'@out_w.T (row0 -> NEG)
        matvec_dual_kernel<<<(HDIM + VDIM + 7) / 8, 512, LDS768, stream>>>(
            copy_w, copy_b, th2, HDIM, HDIM,
            out_w, out_b, gen, VDIM, 1,
            h, HDIM, HDIM + VDIM, 1);
        // tail: css + gen partials -> combine/out/argmax -> sel/embed
        tail_ab_kernel<<<64, 512, 0, stream>>>(enc, th2, gen, css, genM, genZ);
        tail_c_kernel<<<64, 1024, 0, stream>>>(gen, css, inputs, genM, genZ,
                                               dout, argV, argI, t);
        tail_d_kernel<<<BDIM, 1024, 0, stream>>>(enc, css, inputs, argV, argI,
                                                 emb, dout, x, t);
    }
}